// Round 11
// baseline (785.954 us; speedup 1.0000x reference)
//
#include <hip/hip_runtime.h>
#include <stdint.h>

#define B_   8
#define D_   192      // Cin*3
#define N_   2048
#define KNb  11       // k+1

using u32 = uint32_t;
using u16 = unsigned short;
typedef _Float16 f16;
struct alignas(8) h4 { f16 x, y, z, w; };
struct alignas(16) PD16 { h4 p, d; };

typedef __attribute__((ext_vector_type(8)))  short short8;
typedef __attribute__((ext_vector_type(16))) float f32x16;

__device__ __forceinline__ float bf2f(u16 h){ union{u32 i; float f;} x; x.i = ((u32)h) << 16; return x.f; }
__device__ __forceinline__ u16 f2bf(float f){
  union{float f; u32 i;} x; x.f = f;
  u32 r = (x.i + 0x7fffu + ((x.i >> 16) & 1u)) >> 16;
  return (u16)r;
}

// ---------------- K0: bf16 hi transpose + fp32 transpose + f64 xx ----------------
__global__ __launch_bounds__(256) void split_kernel(const float* __restrict__ x,
                                                    short* __restrict__ Xs,
                                                    float* __restrict__ xT,
                                                    double* __restrict__ xxd){
  __shared__ float A[D_ * 64];                       // 48 KB, [d][m]
  const int b = blockIdx.y, m0 = blockIdx.x * 64, t = threadIdx.x;
  const size_t xb = (size_t)b * D_ * N_;
  #pragma unroll
  for (int q = 0; q < 48; ++q){
    int p = t + 256*q;
    int d = p >> 6, i = p & 63;
    A[d*64 + i] = x[xb + (size_t)d*N_ + m0 + i];
  }
  __syncthreads();
  const int m = t & 63, seg = t >> 6;                // 4 segs of 48 d's per point
  short* orow = Xs + ((size_t)b*N_ + m0 + m) * 192;
  #pragma unroll
  for (int c8 = 0; c8 < 6; ++c8){
    union { u16 s[8]; int4 v; } uh;
    #pragma unroll
    for (int j = 0; j < 8; ++j)
      uh.s[j] = f2bf(A[(seg*48 + c8*8 + j)*64 + m]);
    *(int4*)(orow + seg*48 + c8*8) = uh.v;
  }
  {
    float* trow = xT + ((size_t)b*N_ + m0 + m) * 192 + seg*48;
    #pragma unroll
    for (int j = 0; j < 12; ++j){
      float4 v = { A[(seg*48 + 4*j + 0)*64 + m], A[(seg*48 + 4*j + 1)*64 + m],
                   A[(seg*48 + 4*j + 2)*64 + m], A[(seg*48 + 4*j + 3)*64 + m] };
      *(float4*)(trow + 4*j) = v;
    }
  }
  if (t < 64){
    double s = 0.0;
    #pragma unroll 4
    for (int d = 0; d < D_; ++d){ double v = (double)A[d*64 + t]; s = fma(v, v, s); }
    xxd[b*N_ + m0 + t] = s;
  }
}

// ---------------- K1: MFMA kNN v5.1 (hi-only K=192; R10 + scan-drain barrier fix) ----------------
// grid (8 b, 64 stripes of 32 n): linear%8 = b -> XCD-local Xs slice.
// LDS: A 12,288 | B 32,768 (CT 32,896 aliases, +128 pad) | XXS 1,024 | XXN 128 = 46,336
#define KA    0
#define KB    12288
#define KXXS  45184
#define KXXN  46208
#define KSZ   46336
__global__ __launch_bounds__(512, 6) void knn_kernel(const short* __restrict__ Xs,
                                                     const double* __restrict__ xxd,
                                                     u16* __restrict__ cand){
  __shared__ __align__(16) char smem[KSZ];
  float* CT  = (float*)(smem + KB);
  float* XXS = (float*)(smem + KXXS);
  float* XXN = (float*)(smem + KXXN);

  const int b = blockIdx.x, n0 = blockIdx.y * 32;
  const int t = threadIdx.x, lane = t & 63, w = t >> 6;
  const int l31 = lane & 31, lh = lane >> 5;
  const short* xsb = Xs + (size_t)b * N_ * 192;

  // stage A-frags: [ks 0..11][lane][16B] = 768 int4  (dest linear: conflict-free)
  {
    int p = t, ks = p >> 6, ln = p & 63;
    *(int4*)(smem + KA + p*16) =
      *(const int4*)(xsb + (size_t)(n0 + (ln & 31))*192 + ks*16 + (ln >> 5)*8);
    if (t < 256){
      int p2 = t + 512; ks = p2 >> 6; ln = p2 & 63;
      *(int4*)(smem + KA + p2*16) =
        *(const int4*)(xsb + (size_t)(n0 + (ln & 31))*192 + ks*16 + (ln >> 5)*8);
    }
  }
  if (t < 32) XXN[t] = (float)xxd[b*N_ + n0 + t];

  // B staging: thread t -> rows r+64q (q=0..3), chunk ch; swizzled row-local chunk
  const int r = t >> 3, ch = t & 7;
  const int chx = ch ^ ((r >> 1) & 7);
  const int ob0 = r*8 + chx;                         // + 512q
  // B fragment read: row w*32+l31, chunk (2*ks2+lh) ^ rmask
  const int rmask = (l31 >> 1) & 7;
  const int rbase = (w*32 + l31) * 8;

  float bv[10]; int bi[10];
  #pragma unroll
  for (int j = 0; j < 10; ++j){ bv[j] = -3.4e38f; bi[j] = 0; }

  short8 c0, c1, c2, c3;
  {   // initial load: st=0, grp=0
    const short* sp = xsb + (size_t)r*192 + ch*8;
    c0 = *(const short8*)(sp);
    c1 = *(const short8*)(sp + 12288);
    c2 = *(const short8*)(sp + 24576);
    c3 = *(const short8*)(sp + 36864);
  }

  for (int st = 0; st < 8; ++st){
    const int m0 = st * 256;
    if (t < 256) XXS[t] = (float)xxd[b*N_ + m0 + t];

    f32x16 acc = (f32x16)0.0f;
    #pragma unroll
    for (int grp = 0; grp < 3; ++grp){
      __syncthreads();                               // prior B/CT consumers done
      *(short8*)(smem + KB + (ob0       )*16) = c0;
      *(short8*)(smem + KB + (ob0 +  512)*16) = c1;
      *(short8*)(smem + KB + (ob0 + 1024)*16) = c2;
      *(short8*)(smem + KB + (ob0 + 1536)*16) = c3;
      if (!(st == 7 && grp == 2)){                   // prefetch next group
        int nst  = (grp == 2) ? st + 1 : st;
        int ngrp = (grp == 2) ? 0 : grp + 1;
        const short* sp = xsb + (size_t)(nst*256 + r)*192 + ngrp*64 + ch*8;
        c0 = *(const short8*)(sp);
        c1 = *(const short8*)(sp + 12288);
        c2 = *(const short8*)(sp + 24576);
        c3 = *(const short8*)(sp + 36864);
      }
      __syncthreads();                               // B staged
      #pragma unroll
      for (int ks2 = 0; ks2 < 4; ++ks2){
        short8 af = *(const short8*)(smem + KA + (grp*4 + ks2)*1024 + lane*16);
        short8 bf = *(const short8*)(smem + KB + (rbase + ((ks2*2 + lh) ^ rmask))*16);
        acc = __builtin_amdgcn_mfma_f32_32x32x16_bf16(af, bf, acc, 0, 0, 0);
      }
    }
    __syncthreads();                                 // all MFMA B-reads done before CT overwrite

    // scatter acc -> CT[n][m], stride 257 (conflict-free); aliases B
    #pragma unroll
    for (int reg = 0; reg < 16; ++reg){
      int rr = (reg & 3) + 8*(reg >> 2) + 4*lh;
      CT[rr*257 + w*32 + l31] = acc[reg];
    }
    __syncthreads();

    {   // scan: thread (rr = t&31, sub = t>>5) covers 16 m-cols
      const int rr = t & 31, sub = t >> 5;
      const float xn = XXN[rr];
      const float* ct = CT + rr*257 + sub*16;
      const float* xs = XXS + sub*16;
      #pragma unroll
      for (int i = 0; i < 16; ++i){
        float v = 2.f*ct[i] - xs[i] - xn;
        int m = m0 + sub*16 + i;
        if (v > bv[0]){
          bv[0] = v; bi[0] = m;
          #pragma unroll
          for (int s = 0; s < 9; ++s){
            if (bv[s] > bv[s+1]){
              float tv = bv[s]; bv[s] = bv[s+1]; bv[s+1] = tv;
              int   ti = bi[s]; bi[s] = bi[s+1]; bi[s+1] = ti;
            }
          }
        }
      }
    }
    __syncthreads();   // RACE FIX (R10 bug): drain scan readers of XXS/CT before
                       // next st overwrites XXS (write above is pre-barrier) and B.
  }

  // merge 16 lists x 10 per row -> top-32 window (bank-spread rows)
  float* MV = (float*)smem;                          // 512*10*4 = 20,480
  u16*   MI = (u16*)(smem + 20480);                  // 10,240
  {
    const int rr = t & 31, sub = t >> 5;
    #pragma unroll
    for (int j = 0; j < 10; ++j){
      MV[(sub*32 + rr)*10 + j] = bv[j];
      MI[(sub*32 + rr)*10 + j] = (u16)bi[j];
    }
  }
  __syncthreads();
  if (t < 32){
    int head[16];
    #pragma unroll
    for (int q = 0; q < 16; ++q) head[q] = 9;
    const size_t ob = ((size_t)b*N_ + n0 + t) * 32;
    for (int s = 0; s < 32; ++s){
      float bvv = -3.4e38f; int bm = 0x7fffffff, bq = 0;
      #pragma unroll
      for (int q = 0; q < 16; ++q){
        int hh = head[q];
        if (hh >= 0){
          float v = MV[(q*32 + t)*10 + hh];
          int   m = (int)MI[(q*32 + t)*10 + hh];
          if ((v > bvv) || ((v == bvv) && (m < bm))){ bvv = v; bm = m; bq = q; }
        }
      }
      cand[ob + s] = (u16)(bm & 2047);
      #pragma unroll
      for (int q = 0; q < 16; ++q) head[q] -= (q == bq) ? 1 : 0;
    }
  }
}

// ---------------- K1b: f64 refine of 32-window -> top-11 (+ fused neighbor counts) ----------------
__global__ __launch_bounds__(256) void refine_kernel(const float* __restrict__ xT,
                                                     const u16* __restrict__ cand,
                                                     const double* __restrict__ xxd,
                                                     int* __restrict__ idxout,
                                                     int* __restrict__ cnt){
  const int wv = threadIdx.x >> 6, ln = threadIdx.x & 63;
  const int b = blockIdx.x, n = blockIdx.y * 4 + wv;
  const size_t g = (size_t)b*N_ + n;
  const int c5 = ln >> 1, part = ln & 1;
  const int m = (int)cand[g*32 + c5] & 2047;
  const float4* pn = (const float4*)(xT + g*192 + part*96);
  const float4* pm = (const float4*)(xT + ((size_t)b*N_ + m)*192 + part*96);
  double s = 0.0;
  #pragma unroll
  for (int j = 0; j < 24; ++j){
    float4 a = pn[j], bb = pm[j];
    s = fma((double)a.x, (double)bb.x, s);
    s = fma((double)a.y, (double)bb.y, s);
    s = fma((double)a.z, (double)bb.z, s);
    s = fma((double)a.w, (double)bb.w, s);
  }
  s += __shfl_down(s, 1, 64);                        // even lanes hold full dot
  double v = 2.0*s - xxd[g] - xxd[b*N_ + m];
  int rank = 0;
  #pragma unroll
  for (int q = 0; q < 32; ++q){
    double vq = __shfl(v, q*2, 64);
    int    mq = __shfl(m, q*2, 64);
    bool beat = (vq > v) || ((vq == v) && (mq < m));
    rank += beat ? 1 : 0;
  }
  if (part == 0 && rank < KNb){
    idxout[g*KNb + rank] = m;
    atomicAdd(&cnt[b*N_ + m], 1);
  }
}

// ---------------- K2: P/D projection (PD interleaved) + fused BN stats ----------------
__global__ __launch_bounds__(256, 2) void project_kernel(const float* __restrict__ xT,
                                                         const float* __restrict__ Wf,
                                                         const float* __restrict__ Wd,
                                                         PD16* __restrict__ PDb,
                                                         const int* __restrict__ cnt,
                                                         float* __restrict__ gs){
  __shared__ float A[64 * 192];                      // 48 KB, [m][e]
  const int b = blockIdx.x, m0 = blockIdx.y * 64, t = threadIdx.x;
  const int c = t & 63, mg = t >> 6;

  float wf[64], wd[64];
  #pragma unroll
  for (int q = 0; q < 16; ++q){
    float4 uf = *(const float4*)(Wf + c*64 + q*4);
    wf[q*4+0]=uf.x; wf[q*4+1]=uf.y; wf[q*4+2]=uf.z; wf[q*4+3]=uf.w;
    float4 ud = *(const float4*)(Wd + c*64 + q*4);
    wd[q*4+0]=ud.x; wd[q*4+1]=ud.y; wd[q*4+2]=ud.z; wd[q*4+3]=ud.w;
  }
  {
    const float4* src = (const float4*)(xT + ((size_t)b*N_ + m0)*192);
    float4* dst = (float4*)A;
    #pragma unroll
    for (int j = 0; j < 12; ++j) dst[t + 256*j] = src[t + 256*j];
  }
  __syncthreads();

  float sl = 0.f, s2l = 0.f;
  for (int mi = 0; mi < 16; ++mi){
    int m = mg*16 + mi;
    const float4* row = (const float4*)(A + m*192);
    float p[3] = {0.f,0.f,0.f}, qv[3] = {0.f,0.f,0.f};
    #pragma unroll
    for (int v4 = 0; v4 < 48; ++v4){
      float4 f = row[v4];
      const int e = v4*4;
      p [(e+0)%3] = fmaf(wf[(e+0)/3], f.x, p [(e+0)%3]);
      qv[(e+0)%3] = fmaf(wd[(e+0)/3], f.x, qv[(e+0)%3]);
      p [(e+1)%3] = fmaf(wf[(e+1)/3], f.y, p [(e+1)%3]);
      qv[(e+1)%3] = fmaf(wd[(e+1)/3], f.y, qv[(e+1)%3]);
      p [(e+2)%3] = fmaf(wf[(e+2)/3], f.z, p [(e+2)%3]);
      qv[(e+2)%3] = fmaf(wd[(e+2)/3], f.z, qv[(e+2)%3]);
      p [(e+3)%3] = fmaf(wf[(e+3)/3], f.w, p [(e+3)%3]);
      qv[(e+3)%3] = fmaf(wd[(e+3)/3], f.w, qv[(e+3)%3]);
    }
    float nrm = sqrtf(p[0]*p[0] + p[1]*p[1] + p[2]*p[2]);
    float dsq = qv[0]*qv[0] + qv[1]*qv[1] + qv[2]*qv[2];
    union { PD16 pd; int4 v4i; } u;
    u.pd.p.x = (f16)p[0];  u.pd.p.y = (f16)p[1];  u.pd.p.z = (f16)p[2];  u.pd.p.w = (f16)nrm;
    u.pd.d.x = (f16)qv[0]; u.pd.d.y = (f16)qv[1]; u.pd.d.z = (f16)qv[2]; u.pd.d.w = (f16)dsq;
    *(int4*)&PDb[((size_t)b*N_ + m0 + m)*64 + c] = u.v4i;
    float wt = (float)cnt[b*N_ + m0 + m];
    sl  = fmaf(wt, nrm, sl);
    s2l = fmaf(wt*nrm, nrm, s2l);
  }
  __syncthreads();
  float* red = A;                                    // reuse LDS
  red[mg*64 + c] = sl; red[256 + mg*64 + c] = s2l;
  __syncthreads();
  if (mg == 0) atomicAdd(&gs[c],    red[c] + red[64+c] + red[128+c] + red[192+c]);
  if (mg == 1) atomicAdd(&gs[64+c], red[256+c] + red[320+c] + red[384+c] + red[448+c]);
}

// ---------------- K4: gather + BN + nonlinearity + mean over K ----------------
__global__ __launch_bounds__(512) void out_kernel(const PD16* __restrict__ PDb,
                                                  const int* __restrict__ idxin, const float* __restrict__ gs,
                                                  const float* __restrict__ gamma, const float* __restrict__ beta,
                                                  float* __restrict__ outp){
  __shared__ float res[64 * 193];                    // 49,408 B
  const int b  = blockIdx.x;
  const int n0 = blockIdx.y * 64;
  const int t = threadIdx.x, w = t >> 6, c = t & 63;
  const float Ninv = 1.f / (float)(B_*N_*KNb);
  float mean = gs[c] * Ninv;
  float var  = gs[64+c] * Ninv - mean*mean;
  float istd = rsqrtf(var + 1e-5f);
  float sa = istd * gamma[c];
  float be = beta[c];
  const float kinv = 1.f/11.f;
  for (int i = 0; i < 8; ++i){
    int n = n0 + w*8 + i;
    const int* ip = idxin + ((size_t)b*N_ + n)*KNb;
    float a0=0, a1=0, a2=0;
    #pragma unroll
    for (int k = 0; k < KNb; ++k){
      int m = ip[k] & 2047;
      PD16 pd = PDb[((size_t)b*N_ + m)*64 + c];
      float pw = (float)pd.p.w;
      float nb = (pw - mean)*sa + be;
      float sc = nb / pw;
      float p0 = (float)pd.p.x*sc, p1 = (float)pd.p.y*sc, p2 = (float)pd.p.z*sc;
      float d0 = (float)pd.d.x, d1 = (float)pd.d.y, d2 = (float)pd.d.z;
      float dot = p0*d0 + p1*d1 + p2*d2;
      float f = (dot >= 0.f) ? 0.f : dot / ((float)pd.d.w + 1e-6f);
      a0 += p0 - f*d0; a1 += p1 - f*d1; a2 += p2 - f*d2;
    }
    int row = w*8 + i;
    res[row*193 + 3*c + 0] = a0*kinv;
    res[row*193 + 3*c + 1] = a1*kinv;
    res[row*193 + 3*c + 2] = a2*kinv;
  }
  __syncthreads();
  #pragma unroll
  for (int j = 0; j < 6; ++j){
    int p = t + 512*j;
    int cdim = p >> 4, nq = p & 15;
    float4 v = { res[(nq*4 + 0)*193 + cdim], res[(nq*4 + 1)*193 + cdim],
                 res[(nq*4 + 2)*193 + cdim], res[(nq*4 + 3)*193 + cdim] };
    *(float4*)(outp + ((size_t)b*192 + cdim)*N_ + n0 + nq*4) = v;
  }
}

extern "C" void kernel_launch(void* const* d_in, const int* in_sizes, int n_in,
                              void* d_out, int out_size, void* d_ws, size_t ws_size,
                              hipStream_t stream){
  const float* x     = (const float*)d_in[0];
  const float* Wf    = (const float*)d_in[1];
  const float* Wd    = (const float*)d_in[2];
  const float* gamma = (const float*)d_in[3];
  const float* beta  = (const float*)d_in[4];
  float* outp = (float*)d_out;

  // ws >= 30,408,704 B proven in R6.
  char* ws = (char*)d_ws;
  int*    idx  = (int*)   (ws);                 // 720,896
  int*    cnt  = (int*)   (ws + 720896);        // 65,536
  float*  gs   = (float*) (ws + 786432);        // 512
  PD16*   PDb  = (PD16*)  (ws + 1048576);       // 16,777,216 (ends 17,825,792)
  short*  Xs   = (short*) (ws + 1048576);       //   alias: 6,291,456 (hi-only), pre-project
  double* xxd  = (double*)(ws + 13631488);      //   alias: 131,072, pre-project
  u16*    cand = (u16*)   (ws + 13762560);      //   alias: 1,048,576 (32-window), pre-project
  float*  xT   = (float*) (ws + 17825792);      // 12,582,912 (ends 30,408,704)

  hipMemsetAsync(cnt, 0, 66048, stream);        // zero cnt + gs (contiguous)
  split_kernel  <<<dim3(32, 8),  256, 0, stream>>>(x, Xs, xT, xxd);
  knn_kernel    <<<dim3(8, 64),  512, 0, stream>>>(Xs, xxd, cand);
  refine_kernel <<<dim3(8, 512), 256, 0, stream>>>(xT, cand, xxd, idx, cnt);
  project_kernel<<<dim3(8, 32),  256, 0, stream>>>(xT, Wf, Wd, PDb, cnt, gs);
  out_kernel    <<<dim3(8, 32),  512, 0, stream>>>(PDb, idx, gs, gamma, beta, outp);
}

// Round 12
// 429.210 us; speedup vs baseline: 1.8312x; 1.8312x over previous
//
#include <hip/hip_runtime.h>
#include <stdint.h>

#define B_   8
#define D_   192      // Cin*3
#define N_   2048
#define KNb  11       // k+1

using u32 = uint32_t;
using u16 = unsigned short;
typedef _Float16 f16;
struct alignas(8) h4 { f16 x, y, z, w; };
struct alignas(16) PD16 { h4 p, d; };

typedef __attribute__((ext_vector_type(8)))  short short8;
typedef __attribute__((ext_vector_type(16))) float f32x16;

__device__ __forceinline__ float bf2f(u16 h){ union{u32 i; float f;} x; x.i = ((u32)h) << 16; return x.f; }
__device__ __forceinline__ u16 f2bf(float f){
  union{float f; u32 i;} x; x.f = f;
  u32 r = (x.i + 0x7fffu + ((x.i >> 16) & 1u)) >> 16;
  return (u16)r;
}

// ---------------- K0: bf16 hi transpose + fp32 transpose + f64 xx ----------------
__global__ __launch_bounds__(256) void split_kernel(const float* __restrict__ x,
                                                    short* __restrict__ Xs,
                                                    float* __restrict__ xT,
                                                    double* __restrict__ xxd){
  __shared__ float A[D_ * 64];                       // 48 KB, [d][m]
  const int b = blockIdx.y, m0 = blockIdx.x * 64, t = threadIdx.x;
  const size_t xb = (size_t)b * D_ * N_;
  #pragma unroll
  for (int q = 0; q < 48; ++q){
    int p = t + 256*q;
    int d = p >> 6, i = p & 63;
    A[d*64 + i] = x[xb + (size_t)d*N_ + m0 + i];
  }
  __syncthreads();
  const int m = t & 63, seg = t >> 6;                // 4 segs of 48 d's per point
  short* orow = Xs + ((size_t)b*N_ + m0 + m) * 192;
  #pragma unroll
  for (int c8 = 0; c8 < 6; ++c8){
    union { u16 s[8]; int4 v; } uh;
    #pragma unroll
    for (int j = 0; j < 8; ++j)
      uh.s[j] = f2bf(A[(seg*48 + c8*8 + j)*64 + m]);
    *(int4*)(orow + seg*48 + c8*8) = uh.v;
  }
  {
    float* trow = xT + ((size_t)b*N_ + m0 + m) * 192 + seg*48;
    #pragma unroll
    for (int j = 0; j < 12; ++j){
      float4 v = { A[(seg*48 + 4*j + 0)*64 + m], A[(seg*48 + 4*j + 1)*64 + m],
                   A[(seg*48 + 4*j + 2)*64 + m], A[(seg*48 + 4*j + 3)*64 + m] };
      *(float4*)(trow + 4*j) = v;
    }
  }
  if (t < 64){
    double s = 0.0;
    #pragma unroll 4
    for (int d = 0; d < D_; ++d){ double v = (double)A[d*64 + t]; s = fma(v, v, s); }
    xxd[b*N_ + m0 + t] = s;
  }
}

// ---------------- K1: MFMA kNN v5.1 (hi-only K=192) ----------------
#define KA    0
#define KB    12288
#define KXXS  45184
#define KXXN  46208
#define KSZ   46336
__global__ __launch_bounds__(512, 6) void knn_kernel(const short* __restrict__ Xs,
                                                     const double* __restrict__ xxd,
                                                     u16* __restrict__ cand){
  __shared__ __align__(16) char smem[KSZ];
  float* CT  = (float*)(smem + KB);
  float* XXS = (float*)(smem + KXXS);
  float* XXN = (float*)(smem + KXXN);

  const int b = blockIdx.x, n0 = blockIdx.y * 32;
  const int t = threadIdx.x, lane = t & 63, w = t >> 6;
  const int l31 = lane & 31, lh = lane >> 5;
  const short* xsb = Xs + (size_t)b * N_ * 192;

  {
    int p = t, ks = p >> 6, ln = p & 63;
    *(int4*)(smem + KA + p*16) =
      *(const int4*)(xsb + (size_t)(n0 + (ln & 31))*192 + ks*16 + (ln >> 5)*8);
    if (t < 256){
      int p2 = t + 512; ks = p2 >> 6; ln = p2 & 63;
      *(int4*)(smem + KA + p2*16) =
        *(const int4*)(xsb + (size_t)(n0 + (ln & 31))*192 + ks*16 + (ln >> 5)*8);
    }
  }
  if (t < 32) XXN[t] = (float)xxd[b*N_ + n0 + t];

  const int r = t >> 3, ch = t & 7;
  const int chx = ch ^ ((r >> 1) & 7);
  const int ob0 = r*8 + chx;
  const int rmask = (l31 >> 1) & 7;
  const int rbase = (w*32 + l31) * 8;

  float bv[10]; int bi[10];
  #pragma unroll
  for (int j = 0; j < 10; ++j){ bv[j] = -3.4e38f; bi[j] = 0; }

  short8 c0, c1, c2, c3;
  {
    const short* sp = xsb + (size_t)r*192 + ch*8;
    c0 = *(const short8*)(sp);
    c1 = *(const short8*)(sp + 12288);
    c2 = *(const short8*)(sp + 24576);
    c3 = *(const short8*)(sp + 36864);
  }

  for (int st = 0; st < 8; ++st){
    const int m0 = st * 256;
    if (t < 256) XXS[t] = (float)xxd[b*N_ + m0 + t];

    f32x16 acc = (f32x16)0.0f;
    #pragma unroll
    for (int grp = 0; grp < 3; ++grp){
      __syncthreads();
      *(short8*)(smem + KB + (ob0       )*16) = c0;
      *(short8*)(smem + KB + (ob0 +  512)*16) = c1;
      *(short8*)(smem + KB + (ob0 + 1024)*16) = c2;
      *(short8*)(smem + KB + (ob0 + 1536)*16) = c3;
      if (!(st == 7 && grp == 2)){
        int nst  = (grp == 2) ? st + 1 : st;
        int ngrp = (grp == 2) ? 0 : grp + 1;
        const short* sp = xsb + (size_t)(nst*256 + r)*192 + ngrp*64 + ch*8;
        c0 = *(const short8*)(sp);
        c1 = *(const short8*)(sp + 12288);
        c2 = *(const short8*)(sp + 24576);
        c3 = *(const short8*)(sp + 36864);
      }
      __syncthreads();
      #pragma unroll
      for (int ks2 = 0; ks2 < 4; ++ks2){
        short8 af = *(const short8*)(smem + KA + (grp*4 + ks2)*1024 + lane*16);
        short8 bf = *(const short8*)(smem + KB + (rbase + ((ks2*2 + lh) ^ rmask))*16);
        acc = __builtin_amdgcn_mfma_f32_32x32x16_bf16(af, bf, acc, 0, 0, 0);
      }
    }
    __syncthreads();

    #pragma unroll
    for (int reg = 0; reg < 16; ++reg){
      int rr = (reg & 3) + 8*(reg >> 2) + 4*lh;
      CT[rr*257 + w*32 + l31] = acc[reg];
    }
    __syncthreads();

    {
      const int rr = t & 31, sub = t >> 5;
      const float xn = XXN[rr];
      const float* ct = CT + rr*257 + sub*16;
      const float* xs = XXS + sub*16;
      #pragma unroll
      for (int i = 0; i < 16; ++i){
        float v = 2.f*ct[i] - xs[i] - xn;
        int m = m0 + sub*16 + i;
        if (v > bv[0]){
          bv[0] = v; bi[0] = m;
          #pragma unroll
          for (int s = 0; s < 9; ++s){
            if (bv[s] > bv[s+1]){
              float tv = bv[s]; bv[s] = bv[s+1]; bv[s+1] = tv;
              int   ti = bi[s]; bi[s] = bi[s+1]; bi[s+1] = ti;
            }
          }
        }
      }
    }
    __syncthreads();   // drain scan readers before next st overwrites XXS/B
  }

  float* MV = (float*)smem;
  u16*   MI = (u16*)(smem + 20480);
  {
    const int rr = t & 31, sub = t >> 5;
    #pragma unroll
    for (int j = 0; j < 10; ++j){
      MV[(sub*32 + rr)*10 + j] = bv[j];
      MI[(sub*32 + rr)*10 + j] = (u16)bi[j];
    }
  }
  __syncthreads();
  if (t < 32){
    int head[16];
    #pragma unroll
    for (int q = 0; q < 16; ++q) head[q] = 9;
    const size_t ob = ((size_t)b*N_ + n0 + t) * 32;
    for (int s = 0; s < 32; ++s){
      float bvv = -3.4e38f; int bm = 0x7fffffff, bq = 0;
      #pragma unroll
      for (int q = 0; q < 16; ++q){
        int hh = head[q];
        if (hh >= 0){
          float v = MV[(q*32 + t)*10 + hh];
          int   m = (int)MI[(q*32 + t)*10 + hh];
          if ((v > bvv) || ((v == bvv) && (m < bm))){ bvv = v; bm = m; bq = q; }
        }
      }
      cand[ob + s] = (u16)(bm & 2047);
      #pragma unroll
      for (int q = 0; q < 16; ++q) head[q] -= (q == bq) ? 1 : 0;
    }
  }
}

// ---------------- K1b: f64 refine of 32-window -> top-11 (+ fused neighbor counts) ----------------
__global__ __launch_bounds__(256) void refine_kernel(const float* __restrict__ xT,
                                                     const u16* __restrict__ cand,
                                                     const double* __restrict__ xxd,
                                                     int* __restrict__ idxout,
                                                     int* __restrict__ cnt){
  const int wv = threadIdx.x >> 6, ln = threadIdx.x & 63;
  const int b = blockIdx.x, n = blockIdx.y * 4 + wv;
  const size_t g = (size_t)b*N_ + n;
  const int c5 = ln >> 1, part = ln & 1;
  const int m = (int)cand[g*32 + c5] & 2047;
  const float4* pn = (const float4*)(xT + g*192 + part*96);
  const float4* pm = (const float4*)(xT + ((size_t)b*N_ + m)*192 + part*96);
  double s = 0.0;
  #pragma unroll
  for (int j = 0; j < 24; ++j){
    float4 a = pn[j], bb = pm[j];
    s = fma((double)a.x, (double)bb.x, s);
    s = fma((double)a.y, (double)bb.y, s);
    s = fma((double)a.z, (double)bb.z, s);
    s = fma((double)a.w, (double)bb.w, s);
  }
  s += __shfl_down(s, 1, 64);                        // even lanes hold full dot
  double v = 2.0*s - xxd[g] - xxd[b*N_ + m];
  int rank = 0;
  #pragma unroll
  for (int q = 0; q < 32; ++q){
    double vq = __shfl(v, q*2, 64);
    int    mq = __shfl(m, q*2, 64);
    bool beat = (vq > v) || ((vq == v) && (mq < m));
    rank += beat ? 1 : 0;
  }
  if (part == 0 && rank < KNb){
    idxout[g*KNb + rank] = m;
    atomicAdd(&cnt[b*N_ + m], 1);
  }
}

// ---------------- K2: P/D projection + fused BN stats ----------------
// launch_bounds(256,1): grid is 1 block/CU anyway; uncapped VGPRs (cap 512)
// keep wf[64]+wd[64] in registers -- (256,2)'s 128-VGPR cap spilled them (R11: 405us).
__global__ __launch_bounds__(256, 1) void project_kernel(const float* __restrict__ xT,
                                                         const float* __restrict__ Wf,
                                                         const float* __restrict__ Wd,
                                                         PD16* __restrict__ PDb,
                                                         const int* __restrict__ cnt,
                                                         float* __restrict__ gs){
  __shared__ float A[64 * 192];                      // 48 KB, [m][e]
  const int b = blockIdx.x, m0 = blockIdx.y * 64, t = threadIdx.x;
  const int c = t & 63, mg = t >> 6;

  float wf[64], wd[64];
  #pragma unroll
  for (int q = 0; q < 16; ++q){
    float4 uf = *(const float4*)(Wf + c*64 + q*4);
    wf[q*4+0]=uf.x; wf[q*4+1]=uf.y; wf[q*4+2]=uf.z; wf[q*4+3]=uf.w;
    float4 ud = *(const float4*)(Wd + c*64 + q*4);
    wd[q*4+0]=ud.x; wd[q*4+1]=ud.y; wd[q*4+2]=ud.z; wd[q*4+3]=ud.w;
  }
  {
    const float4* src = (const float4*)(xT + ((size_t)b*N_ + m0)*192);
    float4* dst = (float4*)A;
    #pragma unroll
    for (int j = 0; j < 12; ++j) dst[t + 256*j] = src[t + 256*j];
  }
  __syncthreads();

  float sl = 0.f, s2l = 0.f;
  for (int mi = 0; mi < 16; ++mi){
    int m = mg*16 + mi;
    const float4* row = (const float4*)(A + m*192);
    float p[3] = {0.f,0.f,0.f}, qv[3] = {0.f,0.f,0.f};
    #pragma unroll
    for (int v4 = 0; v4 < 48; ++v4){
      float4 f = row[v4];
      const int e = v4*4;
      p [(e+0)%3] = fmaf(wf[(e+0)/3], f.x, p [(e+0)%3]);
      qv[(e+0)%3] = fmaf(wd[(e+0)/3], f.x, qv[(e+0)%3]);
      p [(e+1)%3] = fmaf(wf[(e+1)/3], f.y, p [(e+1)%3]);
      qv[(e+1)%3] = fmaf(wd[(e+1)/3], f.y, qv[(e+1)%3]);
      p [(e+2)%3] = fmaf(wf[(e+2)/3], f.z, p [(e+2)%3]);
      qv[(e+2)%3] = fmaf(wd[(e+2)/3], f.z, qv[(e+2)%3]);
      p [(e+3)%3] = fmaf(wf[(e+3)/3], f.w, p [(e+3)%3]);
      qv[(e+3)%3] = fmaf(wd[(e+3)/3], f.w, qv[(e+3)%3]);
    }
    float nrm = sqrtf(p[0]*p[0] + p[1]*p[1] + p[2]*p[2]);
    float dsq = qv[0]*qv[0] + qv[1]*qv[1] + qv[2]*qv[2];
    union { PD16 pd; int4 v4i; } u;
    u.pd.p.x = (f16)p[0];  u.pd.p.y = (f16)p[1];  u.pd.p.z = (f16)p[2];  u.pd.p.w = (f16)nrm;
    u.pd.d.x = (f16)qv[0]; u.pd.d.y = (f16)qv[1]; u.pd.d.z = (f16)qv[2]; u.pd.d.w = (f16)dsq;
    *(int4*)&PDb[((size_t)b*N_ + m0 + m)*64 + c] = u.v4i;
    float wt = (float)cnt[b*N_ + m0 + m];
    sl  = fmaf(wt, nrm, sl);
    s2l = fmaf(wt*nrm, nrm, s2l);
  }
  __syncthreads();
  float* red = A;                                    // reuse LDS
  red[mg*64 + c] = sl; red[256 + mg*64 + c] = s2l;
  __syncthreads();
  if (mg == 0) atomicAdd(&gs[c],    red[c] + red[64+c] + red[128+c] + red[192+c]);
  if (mg == 1) atomicAdd(&gs[64+c], red[256+c] + red[320+c] + red[384+c] + red[448+c]);
}

// ---------------- K4: gather + BN + nonlinearity + mean over K ----------------
__global__ __launch_bounds__(512) void out_kernel(const PD16* __restrict__ PDb,
                                                  const int* __restrict__ idxin, const float* __restrict__ gs,
                                                  const float* __restrict__ gamma, const float* __restrict__ beta,
                                                  float* __restrict__ outp){
  __shared__ float res[64 * 193];                    // 49,408 B
  const int b  = blockIdx.x;
  const int n0 = blockIdx.y * 64;
  const int t = threadIdx.x, w = t >> 6, c = t & 63;
  const float Ninv = 1.f / (float)(B_*N_*KNb);
  float mean = gs[c] * Ninv;
  float var  = gs[64+c] * Ninv - mean*mean;
  float istd = rsqrtf(var + 1e-5f);
  float sa = istd * gamma[c];
  float be = beta[c];
  const float kinv = 1.f/11.f;
  for (int i = 0; i < 8; ++i){
    int n = n0 + w*8 + i;
    const int* ip = idxin + ((size_t)b*N_ + n)*KNb;
    float a0=0, a1=0, a2=0;
    #pragma unroll
    for (int k = 0; k < KNb; ++k){
      int m = ip[k] & 2047;
      PD16 pd = PDb[((size_t)b*N_ + m)*64 + c];
      float pw = (float)pd.p.w;
      float nb = (pw - mean)*sa + be;
      float sc = nb / pw;
      float p0 = (float)pd.p.x*sc, p1 = (float)pd.p.y*sc, p2 = (float)pd.p.z*sc;
      float d0 = (float)pd.d.x, d1 = (float)pd.d.y, d2 = (float)pd.d.z;
      float dot = p0*d0 + p1*d1 + p2*d2;
      float f = (dot >= 0.f) ? 0.f : dot / ((float)pd.d.w + 1e-6f);
      a0 += p0 - f*d0; a1 += p1 - f*d1; a2 += p2 - f*d2;
    }
    int row = w*8 + i;
    res[row*193 + 3*c + 0] = a0*kinv;
    res[row*193 + 3*c + 1] = a1*kinv;
    res[row*193 + 3*c + 2] = a2*kinv;
  }
  __syncthreads();
  #pragma unroll
  for (int j = 0; j < 6; ++j){
    int p = t + 512*j;
    int cdim = p >> 4, nq = p & 15;
    float4 v = { res[(nq*4 + 0)*193 + cdim], res[(nq*4 + 1)*193 + cdim],
                 res[(nq*4 + 2)*193 + cdim], res[(nq*4 + 3)*193 + cdim] };
    *(float4*)(outp + ((size_t)b*192 + cdim)*N_ + n0 + nq*4) = v;
  }
}

extern "C" void kernel_launch(void* const* d_in, const int* in_sizes, int n_in,
                              void* d_out, int out_size, void* d_ws, size_t ws_size,
                              hipStream_t stream){
  const float* x     = (const float*)d_in[0];
  const float* Wf    = (const float*)d_in[1];
  const float* Wd    = (const float*)d_in[2];
  const float* gamma = (const float*)d_in[3];
  const float* beta  = (const float*)d_in[4];
  float* outp = (float*)d_out;

  // ws >= 30,408,704 B proven in R6.
  char* ws = (char*)d_ws;
  int*    idx  = (int*)   (ws);                 // 720,896
  int*    cnt  = (int*)   (ws + 720896);        // 65,536
  float*  gs   = (float*) (ws + 786432);        // 512
  PD16*   PDb  = (PD16*)  (ws + 1048576);       // 16,777,216 (ends 17,825,792)
  short*  Xs   = (short*) (ws + 1048576);       //   alias: 6,291,456 (hi-only), pre-project
  double* xxd  = (double*)(ws + 13631488);      //   alias: 131,072, pre-project
  u16*    cand = (u16*)   (ws + 13762560);      //   alias: 1,048,576 (32-window), pre-project
  float*  xT   = (float*) (ws + 17825792);      // 12,582,912 (ends 30,408,704)

  hipMemsetAsync(cnt, 0, 66048, stream);        // zero cnt + gs (contiguous)
  split_kernel  <<<dim3(32, 8),  256, 0, stream>>>(x, Xs, xT, xxd);
  knn_kernel    <<<dim3(8, 64),  512, 0, stream>>>(Xs, xxd, cand);
  refine_kernel <<<dim3(8, 512), 256, 0, stream>>>(xT, cand, xxd, idx, cnt);
  project_kernel<<<dim3(8, 32),  256, 0, stream>>>(xT, Wf, Wd, PDb, cnt, gs);
  out_kernel    <<<dim3(8, 32),  512, 0, stream>>>(PDb, idx, gs, gamma, beta, outp);
}